// Round 1
// baseline (460.436 us; speedup 1.0000x reference)
//
#include <hip/hip_runtime.h>

#define B_   512
#define C_   256
#define N_   81                 // tokens per batch (9x9)
#define M_   (B_ * N_)          // 41472
#define KNN  9
#define NP   96                 // padded token count for gram tiling
#define GS   97                 // gram LDS row stride (conflict-free)
#define TS   68                 // GEMM LDS stride (mult of 4 -> b128 aligned)

// ---------------------------------------------------------------- kernel A
// Per batch: Gram matrix G = X^T X (X = [256 x 81] slice of x), d2 from it,
// select 9 smallest per row. Also writes transposed tokens tok[M][C].
__global__ __launch_bounds__(256) void knn_tok_kernel(
    const float* __restrict__ x, float* __restrict__ tok,
    int* __restrict__ knn_idx) {
  __shared__ float lds[NP * GS];   // chunk [64][GS] then G [96][GS]
  __shared__ float sqv[NP];
  const int b = blockIdx.x;
  const int tid = threadIdx.x;
  const float* xb = x + (size_t)b * C_ * N_;
  float* tokb = tok + (size_t)b * N_ * C_;

  const int ti = tid >> 4, tj = tid & 15;
  const int i0 = ti * 6, j0 = tj * 6;
  float acc[6][6];
#pragma unroll
  for (int i = 0; i < 6; ++i)
#pragma unroll
    for (int j = 0; j < 6; ++j) acc[i][j] = 0.f;

  for (int c0 = 0; c0 < C_; c0 += 64) {
    __syncthreads();
    // linear coalesced load of 64x81 chunk
    for (int e = tid; e < 64 * N_; e += 256) {
      lds[(e / N_) * GS + (e % N_)] = xb[c0 * N_ + e];
    }
    __syncthreads();
    // transposed write of tokens (coalesced over c)
    for (int f = tid; f < 64 * N_; f += 256) {
      int n = f >> 6, c = f & 63;
      tokb[n * C_ + c0 + c] = lds[c * GS + n];
    }
    // gram accumulate: 6x6 register tile per thread
    for (int c = 0; c < 64; ++c) {
      const float* row = &lds[c * GS];
      float xi[6], xj[6];
#pragma unroll
      for (int u = 0; u < 6; ++u) { xi[u] = row[i0 + u]; xj[u] = row[j0 + u]; }
#pragma unroll
      for (int i = 0; i < 6; ++i)
#pragma unroll
        for (int j = 0; j < 6; ++j) acc[i][j] += xi[i] * xj[j];
    }
  }
  __syncthreads();
#pragma unroll
  for (int i = 0; i < 6; ++i)
#pragma unroll
    for (int j = 0; j < 6; ++j) lds[(i0 + i) * GS + (j0 + j)] = acc[i][j];
  __syncthreads();
  if (tid < NP) sqv[tid] = lds[tid * GS + tid];
  __syncthreads();
  if (tid < N_) {
    const int n = tid;
    const float sn = sqv[n];
    const float* grow = &lds[n * GS];
    float bd[KNN]; int bi[KNN];
#pragma unroll
    for (int k = 0; k < KNN; ++k) { bd[k] = 3.4e38f; bi[k] = 0; }
    for (int m = 0; m < N_; ++m) {
      float d2 = sn + sqv[m] - 2.f * grow[m];
      int wi = 0; float wv = bd[0];
#pragma unroll
      for (int k = 1; k < KNN; ++k) if (bd[k] > wv) { wv = bd[k]; wi = k; }
      if (d2 < wv) { bd[wi] = d2; bi[wi] = m; }
    }
#pragma unroll
    for (int k = 0; k < KNN; ++k)
      knn_idx[((size_t)b * N_ + n) * KNN + k] = bi[k];
  }
}

// ---------------------------------------------------------------- kernel B
// qkv[m][0:256)=q, [256:512)=k, [512:768)=v.  out = tok @ W^T + bias.
// 64x64 output tile per block, 4x4 microtile per thread, K-chunks of 64.
__global__ __launch_bounds__(256) void qkv_gemm_kernel(
    const float* __restrict__ tok,
    const float* __restrict__ wq, const float* __restrict__ bq,
    const float* __restrict__ wk, const float* __restrict__ bk,
    const float* __restrict__ wv, const float* __restrict__ bv,
    float* __restrict__ qkv) {
  __shared__ float AsT[64 * TS];   // [c][m]
  __shared__ float WsT[64 * TS];   // [c][j]
  const int tid = threadIdx.x;
  const int m0 = blockIdx.x * 64;
  const int jt = blockIdx.y;          // 0..11
  const int sel = jt >> 2;
  const float* W  = sel == 0 ? wq : (sel == 1 ? wk : wv);
  const float* Bb = sel == 0 ? bq : (sel == 1 ? bk : bv);
  const int jl0 = (jt & 3) * 64;

  const int tx = tid & 15, ty = tid >> 4;
  float acc[4][4];
#pragma unroll
  for (int i = 0; i < 4; ++i)
#pragma unroll
    for (int j = 0; j < 4; ++j) acc[i][j] = 0.f;

  for (int k0 = 0; k0 < 256; k0 += 64) {
    __syncthreads();
#pragma unroll
    for (int q = 0; q < 4; ++q) {
      int v = tid + q * 256;          // 0..1023
      int mm = v >> 4;                // 0..63
      int cc = (v & 15) * 4;          // 0..60
      float4 av = *(const float4*)&tok[(size_t)(m0 + mm) * 256 + k0 + cc];
      AsT[(cc + 0) * TS + mm] = av.x;
      AsT[(cc + 1) * TS + mm] = av.y;
      AsT[(cc + 2) * TS + mm] = av.z;
      AsT[(cc + 3) * TS + mm] = av.w;
      float4 wv4 = *(const float4*)&W[(size_t)(jl0 + mm) * 256 + k0 + cc];
      WsT[(cc + 0) * TS + mm] = wv4.x;
      WsT[(cc + 1) * TS + mm] = wv4.y;
      WsT[(cc + 2) * TS + mm] = wv4.z;
      WsT[(cc + 3) * TS + mm] = wv4.w;
    }
    __syncthreads();
    for (int c = 0; c < 64; ++c) {
      float4 a4 = *(const float4*)&AsT[c * TS + ty * 4];
      float4 w4 = *(const float4*)&WsT[c * TS + tx * 4];
      float aa[4] = {a4.x, a4.y, a4.z, a4.w};
      float ww[4] = {w4.x, w4.y, w4.z, w4.w};
#pragma unroll
      for (int i = 0; i < 4; ++i)
#pragma unroll
        for (int j = 0; j < 4; ++j) acc[i][j] += aa[i] * ww[j];
    }
  }
  const float4 b4 = *(const float4*)&Bb[jl0 + tx * 4];
  const float bb[4] = {b4.x, b4.y, b4.z, b4.w};
#pragma unroll
  for (int i = 0; i < 4; ++i) {
    float4 o;
    o.x = acc[i][0] + bb[0];
    o.y = acc[i][1] + bb[1];
    o.z = acc[i][2] + bb[2];
    o.w = acc[i][3] + bb[3];
    *(float4*)&qkv[(size_t)(m0 + ty * 4 + i) * 768 + jt * 64 + tx * 4] = o;
  }
}

// ---------------------------------------------------------------- kernel C
// One block per (b,n). thread = channel c; wave = head. Scores via wave
// shuffle reduce, softmax over 9 neighbors, weighted V sum.
__global__ __launch_bounds__(256) void attn_kernel(
    const float* __restrict__ qkv, const int* __restrict__ knn_idx,
    const float* __restrict__ a, float* __restrict__ outNC) {
  const int m = blockIdx.x;
  const int b = m / N_;
  const int tid = threadIdx.x;
  const float qc = qkv[(size_t)m * 768 + tid];
  const float av = a[tid];
  int nb[KNN];
#pragma unroll
  for (int k = 0; k < KNN; ++k) nb[k] = knn_idx[(size_t)m * KNN + k];
  float sc[KNN];
#pragma unroll
  for (int k = 0; k < KNN; ++k) {
    const size_t mk = (size_t)(b * N_ + nb[k]) * 768;
    float t = qc + qkv[mk + 256 + tid];
    t = t > 0.f ? t : 0.2f * t;
    float p = t * av;
#pragma unroll
    for (int off = 32; off > 0; off >>= 1) p += __shfl_xor(p, off, 64);
    sc[k] = p;
  }
  float mx = sc[0];
#pragma unroll
  for (int k = 1; k < KNN; ++k) mx = fmaxf(mx, sc[k]);
  float s = 0.f;
#pragma unroll
  for (int k = 0; k < KNN; ++k) { sc[k] = expf(sc[k] - mx); s += sc[k]; }
  const float inv = 1.f / s;
  float acc = 0.f;
#pragma unroll
  for (int k = 0; k < KNN; ++k) {
    const size_t mk = (size_t)(b * N_ + nb[k]) * 768;
    acc += (sc[k] * inv) * qkv[mk + 512 + tid];
  }
  outNC[(size_t)m * 256 + tid] = acc;
}

// ---------------------------------------------------------------- kernel D
// Deterministic two-stage BN stats (no atomics -> graph-replay safe).
__global__ __launch_bounds__(256) void bn_partial_kernel(
    const float* __restrict__ outNC, float* __restrict__ ps,
    float* __restrict__ ps2) {
  const int g = blockIdx.x, c = threadIdx.x;
  float s = 0.f, s2 = 0.f;
  for (int r = 0; r < M_ / 256; ++r) {
    float v = outNC[((size_t)g * (M_ / 256) + r) * 256 + c];
    s += v; s2 += v * v;
  }
  ps[g * 256 + c] = s;
  ps2[g * 256 + c] = s2;
}

__global__ __launch_bounds__(256) void bn_finalize_kernel(
    const float* __restrict__ ps, const float* __restrict__ ps2,
    const float* __restrict__ gamma, const float* __restrict__ beta,
    float* __restrict__ scale, float* __restrict__ shift) {
  const int c = threadIdx.x;
  float s = 0.f, s2 = 0.f;
  for (int g = 0; g < 256; ++g) { s += ps[g * 256 + c]; s2 += ps2[g * 256 + c]; }
  const float mean = s * (1.f / (float)M_);
  const float var = s2 * (1.f / (float)M_) - mean * mean;
  const float rstd = rsqrtf(var + 1e-5f);
  scale[c] = gamma[c] * rstd;
  shift[c] = beta[c] - mean * gamma[c] * rstd;
}

// ---------------------------------------------------------------- kernel E
// y = relu(outNC*scale + shift + x), transposed back to [B][C][81] via LDS.
__global__ __launch_bounds__(256) void bn_apply_kernel(
    const float* __restrict__ outNC, const float* __restrict__ x,
    const float* __restrict__ scale, const float* __restrict__ shift,
    float* __restrict__ y) {
  __shared__ float t[N_ * 65];
  const int b = blockIdx.x, tid = threadIdx.x;
  for (int c0 = 0; c0 < 256; c0 += 64) {
    __syncthreads();
    for (int e = tid; e < N_ * 64; e += 256) {
      int n = e >> 6, c = e & 63;
      t[n * 65 + c] = outNC[((size_t)b * N_ + n) * 256 + c0 + c];
    }
    __syncthreads();
    for (int f = tid; f < 64 * N_; f += 256) {
      int c = f / N_, n = f - c * N_;
      float o = t[n * 65 + c];
      size_t gi = (size_t)b * (C_ * N_) + (size_t)(c0 + c) * N_ + n;
      float bn = o * scale[c0 + c] + shift[c0 + c];
      float v = bn + x[gi];
      y[gi] = v > 0.f ? v : 0.f;
    }
  }
}

// ----------------------------------------------------------------
extern "C" void kernel_launch(void* const* d_in, const int* in_sizes, int n_in,
                              void* d_out, int out_size, void* d_ws,
                              size_t ws_size, hipStream_t stream) {
  const float* x     = (const float*)d_in[0];
  const float* wq    = (const float*)d_in[1];
  const float* bq    = (const float*)d_in[2];
  const float* wk    = (const float*)d_in[3];
  const float* bk    = (const float*)d_in[4];
  const float* wv    = (const float*)d_in[5];
  const float* bv    = (const float*)d_in[6];
  const float* a     = (const float*)d_in[7];
  const float* gamma = (const float*)d_in[8];
  const float* beta  = (const float*)d_in[9];
  float* out = (float*)d_out;

  float* qkv   = (float*)d_ws;                     // M*768
  float* tok   = qkv + (size_t)M_ * 768;           // M*256 (reused as outNC)
  int*   kidx  = (int*)(tok + (size_t)M_ * 256);   // M*9 ints
  float* ps    = (float*)(kidx + (size_t)M_ * KNN);// 256*256
  float* ps2   = ps + 256 * 256;                   // 256*256
  float* scale = ps2 + 256 * 256;                  // 256
  float* shift = scale + 256;                      // 256

  knn_tok_kernel<<<B_, 256, 0, stream>>>(x, tok, kidx);
  qkv_gemm_kernel<<<dim3(M_ / 64, 12), 256, 0, stream>>>(
      tok, wq, bq, wk, bk, wv, bv, qkv);
  attn_kernel<<<M_, 256, 0, stream>>>(qkv, kidx, a, tok);  // tok -> outNC
  bn_partial_kernel<<<256, 256, 0, stream>>>(tok, ps, ps2);
  bn_finalize_kernel<<<1, 256, 0, stream>>>(ps, ps2, gamma, beta, scale, shift);
  bn_apply_kernel<<<B_, 256, 0, stream>>>(tok, x, scale, shift, out);
}

// Round 2
// 258.086 us; speedup vs baseline: 1.7840x; 1.7840x over previous
//
#include <hip/hip_runtime.h>
#include <hip/hip_bf16.h>

#define B_   512
#define C_   256
#define N_   81                 // tokens per batch (9x9)
#define M_   (B_ * N_)          // 41472
#define KNN  9
#define NP   96                 // padded token count for gram tiling
#define GS   97                 // gram LDS row stride (conflict-free)

typedef __attribute__((ext_vector_type(8))) short short8;
typedef __attribute__((ext_vector_type(4))) float f32x4;

#define GLD16(g, l) __builtin_amdgcn_global_load_lds(                      \
    (const __attribute__((address_space(1))) void*)(g),                    \
    (__attribute__((address_space(3))) void*)(l), 16, 0, 0)

// ---------------------------------------------------------------- kernel A
// Per batch: Gram matrix G = X^T X, d2 from it, select 9 smallest per row.
// Also writes transposed tokens in BF16: tok[M][C] (GEMM A input).
__global__ __launch_bounds__(256) void knn_tok_kernel(
    const float* __restrict__ x, ushort* __restrict__ tokb,
    int* __restrict__ knn_idx) {
  __shared__ float lds[NP * GS];   // chunk [64][GS] then G [96][GS]
  __shared__ float sqv[NP];
  const int b = blockIdx.x;
  const int tid = threadIdx.x;
  const float* xb = x + (size_t)b * C_ * N_;
  ushort* tb = tokb + (size_t)b * N_ * C_;

  const int ti = tid >> 4, tj = tid & 15;
  const int i0 = ti * 6, j0 = tj * 6;
  float acc[6][6];
#pragma unroll
  for (int i = 0; i < 6; ++i)
#pragma unroll
    for (int j = 0; j < 6; ++j) acc[i][j] = 0.f;

  for (int c0 = 0; c0 < C_; c0 += 64) {
    __syncthreads();
    for (int e = tid; e < 64 * N_; e += 256) {
      lds[(e / N_) * GS + (e % N_)] = xb[c0 * N_ + e];
    }
    __syncthreads();
    // transposed bf16 write of tokens (coalesced over c)
    for (int f = tid; f < 64 * N_; f += 256) {
      int n = f >> 6, c = f & 63;
      __hip_bfloat16 h = __float2bfloat16(lds[c * GS + n]);
      tb[n * C_ + c0 + c] = *(ushort*)&h;
    }
    for (int c = 0; c < 64; ++c) {
      const float* row = &lds[c * GS];
      float xi[6], xj[6];
#pragma unroll
      for (int u = 0; u < 6; ++u) { xi[u] = row[i0 + u]; xj[u] = row[j0 + u]; }
#pragma unroll
      for (int i = 0; i < 6; ++i)
#pragma unroll
        for (int j = 0; j < 6; ++j) acc[i][j] += xi[i] * xj[j];
    }
  }
  __syncthreads();
#pragma unroll
  for (int i = 0; i < 6; ++i)
#pragma unroll
    for (int j = 0; j < 6; ++j) lds[(i0 + i) * GS + (j0 + j)] = acc[i][j];
  __syncthreads();
  if (tid < NP) sqv[tid] = lds[tid * GS + tid];
  __syncthreads();
  if (tid < N_) {
    const int n = tid;
    const float sn = sqv[n];
    const float* grow = &lds[n * GS];
    float bd[KNN]; int bi[KNN];
#pragma unroll
    for (int k = 0; k < KNN; ++k) { bd[k] = 3.4e38f; bi[k] = 0; }
    for (int m = 0; m < N_; ++m) {
      float d2 = sn + sqv[m] - 2.f * grow[m];
      int wi = 0; float wv = bd[0];
#pragma unroll
      for (int k = 1; k < KNN; ++k) if (bd[k] > wv) { wv = bd[k]; wi = k; }
      if (d2 < wv) { bd[wi] = d2; bi[wi] = m; }
    }
#pragma unroll
    for (int k = 0; k < KNN; ++k)
      knn_idx[((size_t)b * N_ + n) * KNN + k] = bi[k];
  }
}

// ---------------------------------------------------------------- kernel W
// Pack wq|wk|wv into bf16 [768][256], biases into fp32 [768].
__global__ __launch_bounds__(256) void pack_w_kernel(
    const float* __restrict__ wq, const float* __restrict__ bq,
    const float* __restrict__ wk, const float* __restrict__ bk,
    const float* __restrict__ wv, const float* __restrict__ bv,
    ushort* __restrict__ wcat, float* __restrict__ bcat) {
  const int j = blockIdx.x, c = threadIdx.x;
  const int sel = j >> 8, jr = j & 255;
  const float* W  = sel == 0 ? wq : (sel == 1 ? wk : wv);
  const float* Bb = sel == 0 ? bq : (sel == 1 ? bk : bv);
  __hip_bfloat16 h = __float2bfloat16(W[jr * 256 + c]);
  wcat[(size_t)j * 256 + c] = *(ushort*)&h;
  if (c == 0) bcat[j] = Bb[jr];
}

// ---------------------------------------------------------------- kernel B
// bf16 MFMA GEMM: qkv[M][768] = tok[M][256] @ wcat^T + bcat.
// 128x128 tile, BK=64, 4 waves (2x2), 4x4 frags of 16x16x32.
// T2 swizzle: LDS linear dest, pre-swizzled global src, swizzled ds_read.
__global__ __launch_bounds__(256) void qkv_mfma_kernel(
    const ushort* __restrict__ tokb, const ushort* __restrict__ wcat,
    const float* __restrict__ bcat, float* __restrict__ qkv) {
  __shared__ ushort At[128 * 64];   // 16 KB, row-major [r][k], swizzled
  __shared__ ushort Bt[128 * 64];   // 16 KB
  const int tid = threadIdx.x;
  const int m0 = blockIdx.x * 128;
  const int j0 = blockIdx.y * 128;
  const int w = tid >> 6, lane = tid & 63;
  const int wr = w >> 1, wc = w & 1;

  // staging: physical byte o -> logical col (o&127) ^ ((row&7)<<4)
  const char* pA[4]; const char* pB[4]; int oL[4];
#pragma unroll
  for (int it = 0; it < 4; ++it) {
    int o = (it * 256 + tid) * 16;
    int r = o >> 7, cp = o & 127;
    int cl = cp ^ ((r & 7) << 4);
    oL[it] = o;
    pA[it] = (const char*)tokb + ((size_t)(m0 + r) * 256) * 2 + cl;
    pB[it] = (const char*)wcat + ((size_t)(j0 + r) * 256) * 2 + cl;
  }

  f32x4 acc[4][4];
#pragma unroll
  for (int i = 0; i < 4; ++i)
#pragma unroll
    for (int j = 0; j < 4; ++j) acc[i][j] = {0.f, 0.f, 0.f, 0.f};

  const int l15 = lane & 15;
  const int sw = (lane & 7) << 4;          // read-side swizzle (row&7 == lane&7)
  const int kgrp = (lane >> 4) << 4;       // k-group byte offset within 64B half

  for (int k0 = 0; k0 < 256; k0 += 64) {
    __syncthreads();
#pragma unroll
    for (int it = 0; it < 4; ++it) {
      GLD16(pA[it] + k0 * 2, (char*)At + oL[it]);
      GLD16(pB[it] + k0 * 2, (char*)Bt + oL[it]);
    }
    __syncthreads();
#pragma unroll
    for (int kk = 0; kk < 2; ++kk) {
      const int cb = (kk * 64 + kgrp) ^ sw;
      short8 am[4], bn[4];
#pragma unroll
      for (int i = 0; i < 4; ++i) {
        const int ra = wr * 64 + i * 16 + l15;
        am[i] = *(const short8*)((const char*)At + ra * 128 + cb);
        const int rb = wc * 64 + i * 16 + l15;
        bn[i] = *(const short8*)((const char*)Bt + rb * 128 + cb);
      }
#pragma unroll
      for (int i = 0; i < 4; ++i)
#pragma unroll
        for (int j = 0; j < 4; ++j)
          acc[i][j] = __builtin_amdgcn_mfma_f32_16x16x32_bf16(
              am[i], bn[j], acc[i][j], 0, 0, 0);
    }
  }

  // epilogue: C[row][col], col=lane&15, row=(lane>>4)*4+reg
#pragma unroll
  for (int j = 0; j < 4; ++j) {
    const int colj = j0 + wc * 64 + j * 16 + l15;
    const float bs = bcat[colj];
#pragma unroll
    for (int i = 0; i < 4; ++i) {
      const int rowm = m0 + wr * 64 + i * 16 + ((lane >> 4) << 2);
#pragma unroll
      for (int reg = 0; reg < 4; ++reg)
        qkv[(size_t)(rowm + reg) * 768 + colj] = acc[i][j][reg] + bs;
    }
  }
}

// ---------------------------------------------------------------- kernel C
// One block per (b,n). thread = channel c; wave = head. Writes its output
// IN PLACE into the q-slot of qkv (no other block ever reads others' q).
__global__ __launch_bounds__(256) void attn_kernel(
    const float* __restrict__ qkvc, const int* __restrict__ knn_idx,
    const float* __restrict__ a, float* __restrict__ qkv) {
  const int m = blockIdx.x;
  const int b = m / N_;
  const int tid = threadIdx.x;
  const float qc = qkvc[(size_t)m * 768 + tid];
  const float av = a[tid];
  int nb[KNN];
#pragma unroll
  for (int k = 0; k < KNN; ++k) nb[k] = knn_idx[(size_t)m * KNN + k];
  float sc[KNN];
#pragma unroll
  for (int k = 0; k < KNN; ++k) {
    const size_t mk = (size_t)(b * N_ + nb[k]) * 768;
    float t = qc + qkvc[mk + 256 + tid];
    t = t > 0.f ? t : 0.2f * t;
    float p = t * av;
#pragma unroll
    for (int off = 32; off > 0; off >>= 1) p += __shfl_xor(p, off, 64);
    sc[k] = p;
  }
  float mx = sc[0];
#pragma unroll
  for (int k = 1; k < KNN; ++k) mx = fmaxf(mx, sc[k]);
  float s = 0.f;
#pragma unroll
  for (int k = 0; k < KNN; ++k) { sc[k] = expf(sc[k] - mx); s += sc[k]; }
  const float inv = 1.f / s;
  float acc = 0.f;
#pragma unroll
  for (int k = 0; k < KNN; ++k) {
    const size_t mk = (size_t)(b * N_ + nb[k]) * 768;
    acc += (sc[k] * inv) * qkvc[mk + 512 + tid];
  }
  qkv[(size_t)m * 768 + tid] = acc;   // overwrite own q-slot
}

// ---------------------------------------------------------------- kernel D
// Deterministic two-stage BN stats over qkv's q-slots (stride 768).
__global__ __launch_bounds__(256) void bn_partial_kernel(
    const float* __restrict__ qkv, float* __restrict__ ps,
    float* __restrict__ ps2) {
  const int g = blockIdx.x, c = threadIdx.x;
  float s = 0.f, s2 = 0.f;
  for (int r = 0; r < M_ / 256; ++r) {
    float v = qkv[((size_t)g * (M_ / 256) + r) * 768 + c];
    s += v; s2 += v * v;
  }
  ps[g * 256 + c] = s;
  ps2[g * 256 + c] = s2;
}

__global__ __launch_bounds__(256) void bn_finalize_kernel(
    const float* __restrict__ ps, const float* __restrict__ ps2,
    const float* __restrict__ gamma, const float* __restrict__ beta,
    float* __restrict__ scale, float* __restrict__ shift) {
  const int c = threadIdx.x;
  float s = 0.f, s2 = 0.f;
  for (int g = 0; g < 256; ++g) { s += ps[g * 256 + c]; s2 += ps2[g * 256 + c]; }
  const float mean = s * (1.f / (float)M_);
  const float var = s2 * (1.f / (float)M_) - mean * mean;
  const float rstd = rsqrtf(var + 1e-5f);
  scale[c] = gamma[c] * rstd;
  shift[c] = beta[c] - mean * gamma[c] * rstd;
}

// ---------------------------------------------------------------- kernel E
// y = relu(attn*scale + shift + x), transposed back to [B][C][81] via LDS.
__global__ __launch_bounds__(256) void bn_apply_kernel(
    const float* __restrict__ qkv, const float* __restrict__ x,
    const float* __restrict__ scale, const float* __restrict__ shift,
    float* __restrict__ y) {
  __shared__ float t[N_ * 65];
  const int b = blockIdx.x, tid = threadIdx.x;
  for (int c0 = 0; c0 < 256; c0 += 64) {
    __syncthreads();
    for (int e = tid; e < N_ * 64; e += 256) {
      int n = e >> 6, c = e & 63;
      t[n * 65 + c] = qkv[((size_t)b * N_ + n) * 768 + c0 + c];
    }
    __syncthreads();
    for (int f = tid; f < 64 * N_; f += 256) {
      int c = f / N_, n = f - c * N_;
      float o = t[n * 65 + c];
      size_t gi = (size_t)b * (C_ * N_) + (size_t)(c0 + c) * N_ + n;
      float bn = o * scale[c0 + c] + shift[c0 + c];
      float v = bn + x[gi];
      y[gi] = v > 0.f ? v : 0.f;
    }
  }
}

// ----------------------------------------------------------------
extern "C" void kernel_launch(void* const* d_in, const int* in_sizes, int n_in,
                              void* d_out, int out_size, void* d_ws,
                              size_t ws_size, hipStream_t stream) {
  const float* x     = (const float*)d_in[0];
  const float* wq    = (const float*)d_in[1];
  const float* bq    = (const float*)d_in[2];
  const float* wk    = (const float*)d_in[3];
  const float* bk    = (const float*)d_in[4];
  const float* wv    = (const float*)d_in[5];
  const float* bv    = (const float*)d_in[6];
  const float* a     = (const float*)d_in[7];
  const float* gamma = (const float*)d_in[8];
  const float* beta  = (const float*)d_in[9];
  float* out = (float*)d_out;

  float*  qkv  = (float*)d_ws;                          // M*768 f32
  ushort* tokb = (ushort*)(qkv + (size_t)M_ * 768);     // M*256 bf16
  ushort* wcat = tokb + (size_t)M_ * 256;               // 768*256 bf16
  float*  bcat = (float*)(wcat + 768 * 256);            // 768 f32
  int*    kidx = (int*)(bcat + 768);                    // M*9 int
  float*  ps   = (float*)(kidx + (size_t)M_ * KNN);     // 256*256
  float*  ps2  = ps + 256 * 256;                        // 256*256
  float*  scale = ps2 + 256 * 256;                      // 256
  float*  shift = scale + 256;                          // 256

  knn_tok_kernel<<<B_, 256, 0, stream>>>(x, tokb, kidx);
  pack_w_kernel<<<768, 256, 0, stream>>>(wq, bq, wk, bk, wv, bv, wcat, bcat);
  qkv_mfma_kernel<<<dim3(M_ / 128, 6), 256, 0, stream>>>(tokb, wcat, bcat, qkv);
  attn_kernel<<<M_, 256, 0, stream>>>(qkv, kidx, a, qkv);
  bn_partial_kernel<<<256, 256, 0, stream>>>(qkv, ps, ps2);
  bn_finalize_kernel<<<1, 256, 0, stream>>>(ps, ps2, gamma, beta, scale, shift);
  bn_apply_kernel<<<B_, 256, 0, stream>>>(qkv, x, scale, shift, out);
}

// Round 3
// 204.856 us; speedup vs baseline: 2.2476x; 1.2598x over previous
//
#include <hip/hip_runtime.h>
#include <hip/hip_bf16.h>

#define B_   512
#define C_   256
#define N_   81                 // tokens per batch (9x9)
#define M_   (B_ * N_)          // 41472
#define KNN  9
#define NP   96                 // padded token count for gram tiling
#define GS   97                 // gram LDS row stride (conflict-free)

typedef __attribute__((ext_vector_type(8))) short short8;
typedef __attribute__((ext_vector_type(4))) float f32x4;

#define GLD16(g, l) __builtin_amdgcn_global_load_lds(                      \
    (const __attribute__((address_space(1))) void*)(g),                    \
    (__attribute__((address_space(3))) void*)(l), 16, 0, 0)

// ---------------------------------------------------------------- kernel A
// Per batch: Gram matrix G = X^T X, d2 from it, select 9 smallest per row.
// Also writes transposed tokens in BF16: tok[M][C] (GEMM A input).
__global__ __launch_bounds__(256) void knn_tok_kernel(
    const float* __restrict__ x, ushort* __restrict__ tokb,
    int* __restrict__ knn_idx) {
  __shared__ float lds[NP * GS];   // chunk [64][GS] then G [96][GS]
  __shared__ float sqv[NP];
  const int b = blockIdx.x;
  const int tid = threadIdx.x;
  const float* xb = x + (size_t)b * C_ * N_;
  ushort* tb = tokb + (size_t)b * N_ * C_;

  const int ti = tid >> 4, tj = tid & 15;
  const int i0 = ti * 6, j0 = tj * 6;
  float acc[6][6];
#pragma unroll
  for (int i = 0; i < 6; ++i)
#pragma unroll
    for (int j = 0; j < 6; ++j) acc[i][j] = 0.f;

  for (int c0 = 0; c0 < C_; c0 += 64) {
    __syncthreads();
    for (int e = tid; e < 64 * N_; e += 256) {
      lds[(e / N_) * GS + (e % N_)] = xb[c0 * N_ + e];
    }
    __syncthreads();
    // transposed bf16 write of tokens (coalesced over c)
    for (int f = tid; f < 64 * N_; f += 256) {
      int n = f >> 6, c = f & 63;
      __hip_bfloat16 h = __float2bfloat16(lds[c * GS + n]);
      tb[n * C_ + c0 + c] = *(ushort*)&h;
    }
    for (int c = 0; c < 64; ++c) {
      const float* row = &lds[c * GS];
      float xi[6], xj[6];
#pragma unroll
      for (int u = 0; u < 6; ++u) { xi[u] = row[i0 + u]; xj[u] = row[j0 + u]; }
#pragma unroll
      for (int i = 0; i < 6; ++i)
#pragma unroll
        for (int j = 0; j < 6; ++j) acc[i][j] += xi[i] * xj[j];
    }
  }
  __syncthreads();
#pragma unroll
  for (int i = 0; i < 6; ++i)
#pragma unroll
    for (int j = 0; j < 6; ++j) lds[(i0 + i) * GS + (j0 + j)] = acc[i][j];
  __syncthreads();
  if (tid < NP) sqv[tid] = lds[tid * GS + tid];
  __syncthreads();
  if (tid < N_) {
    const int n = tid;
    const float sn = sqv[n];
    const float* grow = &lds[n * GS];
    float bd[KNN]; int bi[KNN];
#pragma unroll
    for (int k = 0; k < KNN; ++k) { bd[k] = 3.4e38f; bi[k] = 0; }
    for (int m = 0; m < N_; ++m) {
      float d2 = sn + sqv[m] - 2.f * grow[m];
      int wi = 0; float wv = bd[0];
#pragma unroll
      for (int k = 1; k < KNN; ++k) if (bd[k] > wv) { wv = bd[k]; wi = k; }
      if (d2 < wv) { bd[wi] = d2; bi[wi] = m; }
    }
#pragma unroll
    for (int k = 0; k < KNN; ++k)
      knn_idx[((size_t)b * N_ + n) * KNN + k] = bi[k];
  }
}

// ---------------------------------------------------------------- kernel W
// Pack wq|wk|wv into bf16 [768][256], biases into fp32 [768].
__global__ __launch_bounds__(256) void pack_w_kernel(
    const float* __restrict__ wq, const float* __restrict__ bq,
    const float* __restrict__ wk, const float* __restrict__ bk,
    const float* __restrict__ wv, const float* __restrict__ bv,
    ushort* __restrict__ wcat, float* __restrict__ bcat) {
  const int j = blockIdx.x, c = threadIdx.x;
  const int sel = j >> 8, jr = j & 255;
  const float* W  = sel == 0 ? wq : (sel == 1 ? wk : wv);
  const float* Bb = sel == 0 ? bq : (sel == 1 ? bk : bv);
  __hip_bfloat16 h = __float2bfloat16(W[jr * 256 + c]);
  wcat[(size_t)j * 256 + c] = *(ushort*)&h;
  if (c == 0) bcat[j] = Bb[jr];
}

// ---------------------------------------------------------------- kernel B
// bf16 MFMA GEMM: qkv[M][768] = tok[M][256] @ wcat^T + bcat.
// 128x128 tile, BK=64, 4 waves (2x2), 4x4 frags of 16x16x32.
// T2 swizzle: LDS linear dest, pre-swizzled global src, swizzled ds_read.
__global__ __launch_bounds__(256) void qkv_mfma_kernel(
    const ushort* __restrict__ tokb, const ushort* __restrict__ wcat,
    const float* __restrict__ bcat, float* __restrict__ qkv) {
  __shared__ ushort At[128 * 64];   // 16 KB, row-major [r][k], swizzled
  __shared__ ushort Bt[128 * 64];   // 16 KB
  const int tid = threadIdx.x;
  const int m0 = blockIdx.x * 128;
  const int j0 = blockIdx.y * 128;
  const int w = tid >> 6, lane = tid & 63;
  const int wr = w >> 1, wc = w & 1;

  // staging: physical byte o -> logical col (o&127) ^ ((row&7)<<4)
  const char* pA[4]; const char* pB[4]; int oL[4];
#pragma unroll
  for (int it = 0; it < 4; ++it) {
    int o = (it * 256 + tid) * 16;
    int r = o >> 7, cp = o & 127;
    int cl = cp ^ ((r & 7) << 4);
    oL[it] = o;
    pA[it] = (const char*)tokb + ((size_t)(m0 + r) * 256) * 2 + cl;
    pB[it] = (const char*)wcat + ((size_t)(j0 + r) * 256) * 2 + cl;
  }

  f32x4 acc[4][4];
#pragma unroll
  for (int i = 0; i < 4; ++i)
#pragma unroll
    for (int j = 0; j < 4; ++j) acc[i][j] = {0.f, 0.f, 0.f, 0.f};

  const int l15 = lane & 15;
  const int sw = (lane & 7) << 4;          // read-side swizzle (row&7 == lane&7)
  const int kgrp = (lane >> 4) << 4;       // k-group byte offset within 64B half

  for (int k0 = 0; k0 < 256; k0 += 64) {
    __syncthreads();
#pragma unroll
    for (int it = 0; it < 4; ++it) {
      GLD16(pA[it] + k0 * 2, (char*)At + oL[it]);
      GLD16(pB[it] + k0 * 2, (char*)Bt + oL[it]);
    }
    __syncthreads();
#pragma unroll
    for (int kk = 0; kk < 2; ++kk) {
      const int cb = (kk * 64 + kgrp) ^ sw;
      short8 am[4], bn[4];
#pragma unroll
      for (int i = 0; i < 4; ++i) {
        const int ra = wr * 64 + i * 16 + l15;
        am[i] = *(const short8*)((const char*)At + ra * 128 + cb);
        const int rb = wc * 64 + i * 16 + l15;
        bn[i] = *(const short8*)((const char*)Bt + rb * 128 + cb);
      }
#pragma unroll
      for (int i = 0; i < 4; ++i)
#pragma unroll
        for (int j = 0; j < 4; ++j)
          acc[i][j] = __builtin_amdgcn_mfma_f32_16x16x32_bf16(
              am[i], bn[j], acc[i][j], 0, 0, 0);
    }
  }

  // epilogue: C[row][col], col=lane&15, row=(lane>>4)*4+reg
#pragma unroll
  for (int j = 0; j < 4; ++j) {
    const int colj = j0 + wc * 64 + j * 16 + l15;
    const float bs = bcat[colj];
#pragma unroll
    for (int i = 0; i < 4; ++i) {
      const int rowm = m0 + wr * 64 + i * 16 + ((lane >> 4) << 2);
#pragma unroll
      for (int reg = 0; reg < 4; ++reg)
        qkv[(size_t)(rowm + reg) * 768 + colj] = acc[i][j][reg] + bs;
    }
  }
}

// ---------------------------------------------------------------- kernel C
// One WAVE per token. 16 lanes per head, each lane owns 4 dims (float4).
// Score reduce = 4 shuffle rounds over 16 lanes. exp via v_exp_f32 (exp2).
// Writes output in place into the q-slot of qkv.
__global__ __launch_bounds__(256) void attn_kernel(
    const float* __restrict__ qkvc, const int* __restrict__ knn_idx,
    const float* __restrict__ a, float* __restrict__ qkv) {
  const int nwg = M_ / 4;                    // 10368 = 8 * 1296
  const int bid = blockIdx.x;
  const int swz = (bid & 7) * (nwg / 8) + (bid >> 3);  // XCD-contiguous
  const int w = threadIdx.x >> 6, lane = threadIdx.x & 63;
  const int m = swz * 4 + w;                 // this wave's token
  const int b = m / N_;
  const int bbase = b * N_;

  const f32x4 q4 = *(const f32x4*)&qkvc[(size_t)m * 768 + lane * 4];
  const f32x4 a4 = *(const f32x4*)&a[lane * 4];

  float sc[KNN];
  int nb[KNN];
#pragma unroll
  for (int k = 0; k < KNN; ++k) {
    int nbk = knn_idx[(size_t)m * KNN + k];
    nbk = __builtin_amdgcn_readfirstlane(nbk);
    nb[k] = nbk;
    const float* krow = qkvc + (size_t)(bbase + nbk) * 768 + 256;
    const f32x4 k4 = *(const f32x4*)&krow[lane * 4];
    float p = 0.f;
#pragma unroll
    for (int u = 0; u < 4; ++u) {
      float t = q4[u] + k4[u];
      t = fmaxf(t, 0.2f * t);                // leaky_relu(t, 0.2)
      p = __builtin_fmaf(t, a4[u], p);
    }
    // reduce over the 16-lane head group
    p += __shfl_xor(p, 1, 16);
    p += __shfl_xor(p, 2, 16);
    p += __shfl_xor(p, 4, 16);
    p += __shfl_xor(p, 8, 16);
    sc[k] = p;
  }
  float mx = sc[0];
#pragma unroll
  for (int k = 1; k < KNN; ++k) mx = fmaxf(mx, sc[k]);
  float s = 0.f;
#pragma unroll
  for (int k = 0; k < KNN; ++k) {
    sc[k] = __builtin_amdgcn_exp2f((sc[k] - mx) * 1.44269504f);
    s += sc[k];
  }
  const float inv = __builtin_amdgcn_rcpf(s);
  f32x4 acc = {0.f, 0.f, 0.f, 0.f};
#pragma unroll
  for (int k = 0; k < KNN; ++k) {
    const float* vrow = qkvc + (size_t)(bbase + nb[k]) * 768 + 512;
    const f32x4 v4 = *(const f32x4*)&vrow[lane * 4];
    const float wk_ = sc[k] * inv;
#pragma unroll
    for (int u = 0; u < 4; ++u) acc[u] = __builtin_fmaf(wk_, v4[u], acc[u]);
  }
  *(f32x4*)&qkv[(size_t)m * 768 + lane * 4] = acc;   // overwrite own q-slot
}

// ---------------------------------------------------------------- kernel D
// Deterministic two-stage BN stats over qkv's q-slots (stride 768).
__global__ __launch_bounds__(256) void bn_partial_kernel(
    const float* __restrict__ qkv, float* __restrict__ ps,
    float* __restrict__ ps2) {
  const int g = blockIdx.x, c = threadIdx.x;
  float s = 0.f, s2 = 0.f;
  for (int r = 0; r < M_ / 256; ++r) {
    float v = qkv[((size_t)g * (M_ / 256) + r) * 768 + c];
    s += v; s2 += v * v;
  }
  ps[g * 256 + c] = s;
  ps2[g * 256 + c] = s2;
}

__global__ __launch_bounds__(256) void bn_finalize_kernel(
    const float* __restrict__ ps, const float* __restrict__ ps2,
    const float* __restrict__ gamma, const float* __restrict__ beta,
    float* __restrict__ scale, float* __restrict__ shift) {
  const int c = threadIdx.x;
  float s = 0.f, s2 = 0.f;
  for (int g = 0; g < 256; ++g) { s += ps[g * 256 + c]; s2 += ps2[g * 256 + c]; }
  const float mean = s * (1.f / (float)M_);
  const float var = s2 * (1.f / (float)M_) - mean * mean;
  const float rstd = rsqrtf(var + 1e-5f);
  scale[c] = gamma[c] * rstd;
  shift[c] = beta[c] - mean * gamma[c] * rstd;
}

// ---------------------------------------------------------------- kernel E
// y = relu(attn*scale + shift + x), transposed back to [B][C][81] via LDS.
__global__ __launch_bounds__(256) void bn_apply_kernel(
    const float* __restrict__ qkv, const float* __restrict__ x,
    const float* __restrict__ scale, const float* __restrict__ shift,
    float* __restrict__ y) {
  __shared__ float t[N_ * 65];
  const int b = blockIdx.x, tid = threadIdx.x;
  for (int c0 = 0; c0 < 256; c0 += 64) {
    __syncthreads();
    for (int e = tid; e < N_ * 64; e += 256) {
      int n = e >> 6, c = e & 63;
      t[n * 65 + c] = qkv[((size_t)b * N_ + n) * 768 + c0 + c];
    }
    __syncthreads();
    for (int f = tid; f < 64 * N_; f += 256) {
      int c = f / N_, n = f - c * N_;
      float o = t[n * 65 + c];
      size_t gi = (size_t)b * (C_ * N_) + (size_t)(c0 + c) * N_ + n;
      float bn = o * scale[c0 + c] + shift[c0 + c];
      float v = bn + x[gi];
      y[gi] = v > 0.f ? v : 0.f;
    }
  }
}

// ----------------------------------------------------------------
extern "C" void kernel_launch(void* const* d_in, const int* in_sizes, int n_in,
                              void* d_out, int out_size, void* d_ws,
                              size_t ws_size, hipStream_t stream) {
  const float* x     = (const float*)d_in[0];
  const float* wq    = (const float*)d_in[1];
  const float* bq    = (const float*)d_in[2];
  const float* wk    = (const float*)d_in[3];
  const float* bk    = (const float*)d_in[4];
  const float* wv    = (const float*)d_in[5];
  const float* bv    = (const float*)d_in[6];
  const float* a     = (const float*)d_in[7];
  const float* gamma = (const float*)d_in[8];
  const float* beta  = (const float*)d_in[9];
  float* out = (float*)d_out;

  float*  qkv  = (float*)d_ws;                          // M*768 f32
  ushort* tokb = (ushort*)(qkv + (size_t)M_ * 768);     // M*256 bf16
  ushort* wcat = tokb + (size_t)M_ * 256;               // 768*256 bf16
  float*  bcat = (float*)(wcat + 768 * 256);            // 768 f32
  int*    kidx = (int*)(bcat + 768);                    // M*9 int
  float*  ps   = (float*)(kidx + (size_t)M_ * KNN);     // 256*256
  float*  ps2  = ps + 256 * 256;                        // 256*256
  float*  scale = ps2 + 256 * 256;                      // 256
  float*  shift = scale + 256;                          // 256

  knn_tok_kernel<<<B_, 256, 0, stream>>>(x, tokb, kidx);
  pack_w_kernel<<<768, 256, 0, stream>>>(wq, bq, wk, bk, wv, bv, wcat, bcat);
  qkv_mfma_kernel<<<dim3(M_ / 128, 6), 256, 0, stream>>>(tokb, wcat, bcat, qkv);
  attn_kernel<<<M_ / 4, 256, 0, stream>>>(qkv, kidx, a, qkv);
  bn_partial_kernel<<<256, 256, 0, stream>>>(qkv, ps, ps2);
  bn_finalize_kernel<<<1, 256, 0, stream>>>(ps, ps2, gamma, beta, scale, shift);
  bn_apply_kernel<<<B_, 256, 0, stream>>>(qkv, x, scale, shift, out);
}

// Round 5
// 180.359 us; speedup vs baseline: 2.5529x; 1.1358x over previous
//
#include <hip/hip_runtime.h>
#include <hip/hip_bf16.h>

#define B_   512
#define C_   256
#define N_   81                 // tokens per batch (9x9)
#define M_   (B_ * N_)          // 41472
#define KNN  9

typedef __attribute__((ext_vector_type(8))) short short8;
typedef __attribute__((ext_vector_type(4))) float f32x4;

#define GLD16(g, l) __builtin_amdgcn_global_load_lds(                      \
    (const __attribute__((address_space(1))) void*)(g),                    \
    (__attribute__((address_space(3))) void*)(l), 16, 0, 0)

// ---------------------------------------------------------------- kernel A
// Per batch: Gram via MFMA on full hi/lo bf16 split
//   G = hi.hiT + hi.loT + lo.hiT + lo.loT  (= x.xT up to ~4e-5)
// plus EXACT fp32 diagonal sq[n] = sum_c x[c,n]^2 accumulated from raw LDS
// (diag via MFMA was the round-4 accuracy bug: ~3e-4 noise flipped knn picks).
// Then d2 + 9-smallest selection. Also emits tokb (bf16 hi) for the GEMM.
// LDS: raw fp32 chunk [64][81] (20736 B) | hiT [96][64] bf16 swz (12288 B)
//      | loT (12288 B); G [96][97] f32 (37248 B) overlays raw+hi afterwards.
__global__ __launch_bounds__(256) void knn_tok_kernel(
    const float* __restrict__ x, ushort* __restrict__ tokb,
    int* __restrict__ knn_idx) {
  __shared__ __align__(16) char smem[45312];
  __shared__ float sqv[96];
  float*  raw = (float*)smem;
  ushort* hiT = (ushort*)(smem + 20736);
  ushort* loT = (ushort*)(smem + 33024);

  const int b = blockIdx.x;
  const int tid = threadIdx.x;
  const float* xb = x + (size_t)b * C_ * N_;

  const int w = tid >> 6, lane = tid & 63;
  const int wr = w >> 1, wc = w & 1;          // 48x48 quadrant of G
  const int l15 = lane & 15;
  const int sw = (lane & 7) << 4;             // read-side swizzle
  const int kgrp = (lane >> 4) << 4;          // 16-B k-group per lane quarter

  // zero pad rows 81..95 of hiT/loT once (staging only writes n<81)
  for (int p = tid; p < 15 * 32; p += 256) {
    int n = 81 + (p >> 5), q = p & 31;
    int off = n * 128 + ((q * 4) ^ ((n & 7) << 4));
    *(uint*)((char*)hiT + off) = 0u;
    *(uint*)((char*)loT + off) = 0u;
  }

  f32x4 acc[3][3];
#pragma unroll
  for (int i = 0; i < 3; ++i)
#pragma unroll
    for (int j = 0; j < 3; ++j) acc[i][j] = {0.f, 0.f, 0.f, 0.f};
  float sqacc = 0.f;                           // exact fp32 |token|^2

  for (int ch = 0; ch < 4; ++ch) {
    __syncthreads();
    // coalesced float4 load of 64x81 chunk (5184 floats)
    const float* src = xb + ch * 64 * N_;
#pragma unroll
    for (int it = 0; it < 6; ++it) {
      int e4 = tid + it * 256;
      if (e4 < 1296) *(f32x4*)&raw[e4 * 4] = *(const f32x4*)&src[e4 * 4];
    }
    __syncthreads();
    // transpose + hi/lo split + swizzled LDS write + tokb global write
#pragma unroll
    for (int it = 0; it < 11; ++it) {
      int p = tid + it * 256;
      if (p < 2592) {                 // p = n*32 + q, channels c = 2q, 2q+1
        int n = p >> 5, q = p & 31;
        float v0 = raw[(2 * q) * N_ + n];
        float v1 = raw[(2 * q + 1) * N_ + n];
        __hip_bfloat16 h0 = __float2bfloat16(v0);
        __hip_bfloat16 h1 = __float2bfloat16(v1);
        float r0 = v0 - __bfloat162float(h0);
        float r1 = v1 - __bfloat162float(h1);
        __hip_bfloat16 g0 = __float2bfloat16(r0);
        __hip_bfloat16 g1 = __float2bfloat16(r1);
        uint hp = (uint)(*(ushort*)&h0) | ((uint)(*(ushort*)&h1) << 16);
        uint lp = (uint)(*(ushort*)&g0) | ((uint)(*(ushort*)&g1) << 16);
        int off = n * 128 + ((q * 4) ^ ((n & 7) << 4));
        *(uint*)((char*)hiT + off) = hp;
        *(uint*)((char*)loT + off) = lp;
        *(uint*)&tokb[((size_t)(b * N_ + n)) * 256 + ch * 64 + 2 * q] = hp;
      }
    }
    // exact fp32 norms from raw (read-only on raw, same window as transpose)
    if (tid < N_) {
#pragma unroll
      for (int c = 0; c < 64; ++c) {
        float v = raw[c * N_ + tid];
        sqacc = __builtin_fmaf(v, v, sqacc);
      }
    }
    __syncthreads();
    // MFMA: accumulate this chunk's contribution to G quadrant
#pragma unroll
    for (int kk = 0; kk < 2; ++kk) {
      const int cb = (kk * 64 + kgrp) ^ sw;
      short8 ah[3], al[3], bh[3], bl[3];
#pragma unroll
      for (int i = 0; i < 3; ++i) {
        const int ra = wr * 48 + i * 16 + l15;
        ah[i] = *(const short8*)((const char*)hiT + ra * 128 + cb);
        al[i] = *(const short8*)((const char*)loT + ra * 128 + cb);
        const int rb = wc * 48 + i * 16 + l15;
        bh[i] = *(const short8*)((const char*)hiT + rb * 128 + cb);
        bl[i] = *(const short8*)((const char*)loT + rb * 128 + cb);
      }
#pragma unroll
      for (int i = 0; i < 3; ++i)
#pragma unroll
        for (int j = 0; j < 3; ++j) {
          acc[i][j] = __builtin_amdgcn_mfma_f32_16x16x32_bf16(
              ah[i], bh[j], acc[i][j], 0, 0, 0);
          acc[i][j] = __builtin_amdgcn_mfma_f32_16x16x32_bf16(
              ah[i], bl[j], acc[i][j], 0, 0, 0);
          acc[i][j] = __builtin_amdgcn_mfma_f32_16x16x32_bf16(
              al[i], bh[j], acc[i][j], 0, 0, 0);
          acc[i][j] = __builtin_amdgcn_mfma_f32_16x16x32_bf16(
              al[i], bl[j], acc[i][j], 0, 0, 0);
        }
    }
  }
  __syncthreads();   // all MFMAs done before G overlays raw/hiT
  // G epilogue: row=(lane>>4)*4+reg, col=lane&15 within each 16x16 frag
  float* G = (float*)smem;
#pragma unroll
  for (int i = 0; i < 3; ++i) {
    const int row0 = wr * 48 + i * 16 + ((lane >> 4) << 2);
#pragma unroll
    for (int j = 0; j < 3; ++j) {
      const int col = wc * 48 + j * 16 + l15;
#pragma unroll
      for (int reg = 0; reg < 4; ++reg)
        G[(row0 + reg) * 97 + col] = acc[i][j][reg];
    }
  }
  __syncthreads();
  if (tid < N_) sqv[tid] = sqacc;              // exact fp32 diagonal
  __syncthreads();
  if (tid < N_) {
    const int n = tid;
    const float sn = sqv[n];
    const float* grow = &G[n * 97];
    float bd[KNN]; int bi[KNN];
#pragma unroll
    for (int k = 0; k < KNN; ++k) { bd[k] = 3.4e38f; bi[k] = 0; }
    for (int m = 0; m < N_; ++m) {
      float d2 = sn + sqv[m] - 2.f * grow[m];
      int wi = 0; float wv = bd[0];
#pragma unroll
      for (int k = 1; k < KNN; ++k) if (bd[k] > wv) { wv = bd[k]; wi = k; }
      if (d2 < wv) { bd[wi] = d2; bi[wi] = m; }
    }
#pragma unroll
    for (int k = 0; k < KNN; ++k)
      knn_idx[((size_t)b * N_ + n) * KNN + k] = bi[k];
  }
}

// ---------------------------------------------------------------- kernel W
// Pack wq|wk|wv into bf16 [768][256], biases into fp32 [768].
__global__ __launch_bounds__(256) void pack_w_kernel(
    const float* __restrict__ wq, const float* __restrict__ bq,
    const float* __restrict__ wk, const float* __restrict__ bk,
    const float* __restrict__ wv, const float* __restrict__ bv,
    ushort* __restrict__ wcat, float* __restrict__ bcat) {
  const int j = blockIdx.x, c = threadIdx.x;
  const int sel = j >> 8, jr = j & 255;
  const float* W  = sel == 0 ? wq : (sel == 1 ? wk : wv);
  const float* Bb = sel == 0 ? bq : (sel == 1 ? bk : bv);
  __hip_bfloat16 h = __float2bfloat16(W[jr * 256 + c]);
  wcat[(size_t)j * 256 + c] = *(ushort*)&h;
  if (c == 0) bcat[j] = Bb[jr];
}

// ---------------------------------------------------------------- kernel B
// bf16 MFMA GEMM: qkv[M][768] = tok[M][256] @ wcat^T + bcat.
// 128x128 tile, BK=64, 4 waves (2x2), 4x4 frags of 16x16x32.
// T2 swizzle: LDS linear dest, pre-swizzled global src, swizzled ds_read.
__global__ __launch_bounds__(256) void qkv_mfma_kernel(
    const ushort* __restrict__ tokb, const ushort* __restrict__ wcat,
    const float* __restrict__ bcat, float* __restrict__ qkv) {
  __shared__ ushort At[128 * 64];   // 16 KB, row-major [r][k], swizzled
  __shared__ ushort Bt[128 * 64];   // 16 KB
  const int tid = threadIdx.x;
  const int m0 = blockIdx.x * 128;
  const int j0 = blockIdx.y * 128;
  const int w = tid >> 6, lane = tid & 63;
  const int wr = w >> 1, wc = w & 1;

  // staging: physical byte o -> logical col (o&127) ^ ((row&7)<<4)
  const char* pA[4]; const char* pB[4]; int oL[4];
#pragma unroll
  for (int it = 0; it < 4; ++it) {
    int o = (it * 256 + tid) * 16;
    int r = o >> 7, cp = o & 127;
    int cl = cp ^ ((r & 7) << 4);
    oL[it] = o;
    pA[it] = (const char*)tokb + ((size_t)(m0 + r) * 256) * 2 + cl;
    pB[it] = (const char*)wcat + ((size_t)(j0 + r) * 256) * 2 + cl;
  }

  f32x4 acc[4][4];
#pragma unroll
  for (int i = 0; i < 4; ++i)
#pragma unroll
    for (int j = 0; j < 4; ++j) acc[i][j] = {0.f, 0.f, 0.f, 0.f};

  const int l15 = lane & 15;
  const int sw = (lane & 7) << 4;          // read-side swizzle (row&7 == lane&7)
  const int kgrp = (lane >> 4) << 4;       // k-group byte offset within 64B half

  for (int k0 = 0; k0 < 256; k0 += 64) {
    __syncthreads();
#pragma unroll
    for (int it = 0; it < 4; ++it) {
      GLD16(pA[it] + k0 * 2, (char*)At + oL[it]);
      GLD16(pB[it] + k0 * 2, (char*)Bt + oL[it]);
    }
    __syncthreads();
#pragma unroll
    for (int kk = 0; kk < 2; ++kk) {
      const int cb = (kk * 64 + kgrp) ^ sw;
      short8 am[4], bn[4];
#pragma unroll
      for (int i = 0; i < 4; ++i) {
        const int ra = wr * 64 + i * 16 + l15;
        am[i] = *(const short8*)((const char*)At + ra * 128 + cb);
        const int rb = wc * 64 + i * 16 + l15;
        bn[i] = *(const short8*)((const char*)Bt + rb * 128 + cb);
      }
#pragma unroll
      for (int i = 0; i < 4; ++i)
#pragma unroll
        for (int j = 0; j < 4; ++j)
          acc[i][j] = __builtin_amdgcn_mfma_f32_16x16x32_bf16(
              am[i], bn[j], acc[i][j], 0, 0, 0);
    }
  }

  // epilogue: C[row][col], col=lane&15, row=(lane>>4)*4+reg
#pragma unroll
  for (int j = 0; j < 4; ++j) {
    const int colj = j0 + wc * 64 + j * 16 + l15;
    const float bs = bcat[colj];
#pragma unroll
    for (int i = 0; i < 4; ++i) {
      const int rowm = m0 + wr * 64 + i * 16 + ((lane >> 4) << 2);
#pragma unroll
      for (int reg = 0; reg < 4; ++reg)
        qkv[(size_t)(rowm + reg) * 768 + colj] = acc[i][j][reg] + bs;
    }
  }
}

// ---------------------------------------------------------------- kernel C
// One WAVE per token. 16 lanes per head, each lane owns 4 dims (float4).
// Score reduce = 4 shuffle rounds over 16 lanes. exp via v_exp_f32 (exp2).
// Writes output in place into the q-slot of qkv.
__global__ __launch_bounds__(256) void attn_kernel(
    const float* __restrict__ qkvc, const int* __restrict__ knn_idx,
    const float* __restrict__ a, float* __restrict__ qkv) {
  const int nwg = M_ / 4;                    // 10368 = 8 * 1296
  const int bid = blockIdx.x;
  const int swz = (bid & 7) * (nwg / 8) + (bid >> 3);  // XCD-contiguous
  const int w = threadIdx.x >> 6, lane = threadIdx.x & 63;
  const int m = swz * 4 + w;                 // this wave's token
  const int b = m / N_;
  const int bbase = b * N_;

  const f32x4 q4 = *(const f32x4*)&qkvc[(size_t)m * 768 + lane * 4];
  const f32x4 a4 = *(const f32x4*)&a[lane * 4];

  float sc[KNN];
  int nb[KNN];
#pragma unroll
  for (int k = 0; k < KNN; ++k) {
    int nbk = knn_idx[(size_t)m * KNN + k];
    nbk = __builtin_amdgcn_readfirstlane(nbk);
    nb[k] = nbk;
    const float* krow = qkvc + (size_t)(bbase + nbk) * 768 + 256;
    const f32x4 k4 = *(const f32x4*)&krow[lane * 4];
    float p = 0.f;
#pragma unroll
    for (int u = 0; u < 4; ++u) {
      float t = q4[u] + k4[u];
      t = fmaxf(t, 0.2f * t);                // leaky_relu(t, 0.2)
      p = __builtin_fmaf(t, a4[u], p);
    }
    // reduce over the 16-lane head group
    p += __shfl_xor(p, 1, 16);
    p += __shfl_xor(p, 2, 16);
    p += __shfl_xor(p, 4, 16);
    p += __shfl_xor(p, 8, 16);
    sc[k] = p;
  }
  float mx = sc[0];
#pragma unroll
  for (int k = 1; k < KNN; ++k) mx = fmaxf(mx, sc[k]);
  float s = 0.f;
#pragma unroll
  for (int k = 0; k < KNN; ++k) {
    sc[k] = __builtin_amdgcn_exp2f((sc[k] - mx) * 1.44269504f);
    s += sc[k];
  }
  const float inv = __builtin_amdgcn_rcpf(s);
  f32x4 acc = {0.f, 0.f, 0.f, 0.f};
#pragma unroll
  for (int k = 0; k < KNN; ++k) {
    const float* vrow = qkvc + (size_t)(bbase + nb[k]) * 768 + 512;
    const f32x4 v4 = *(const f32x4*)&vrow[lane * 4];
    const float wk_ = sc[k] * inv;
#pragma unroll
    for (int u = 0; u < 4; ++u) acc[u] = __builtin_fmaf(wk_, v4[u], acc[u]);
  }
  *(f32x4*)&qkv[(size_t)m * 768 + lane * 4] = acc;   // overwrite own q-slot
}

// ---------------------------------------------------------------- kernel D
// Deterministic two-stage BN stats over qkv's q-slots (stride 768).
__global__ __launch_bounds__(256) void bn_partial_kernel(
    const float* __restrict__ qkv, float* __restrict__ ps,
    float* __restrict__ ps2) {
  const int g = blockIdx.x, c = threadIdx.x;
  float s = 0.f, s2 = 0.f;
  for (int r = 0; r < M_ / 256; ++r) {
    float v = qkv[((size_t)g * (M_ / 256) + r) * 768 + c];
    s += v; s2 += v * v;
  }
  ps[g * 256 + c] = s;
  ps2[g * 256 + c] = s2;
}

__global__ __launch_bounds__(256) void bn_finalize_kernel(
    const float* __restrict__ ps, const float* __restrict__ ps2,
    const float* __restrict__ gamma, const float* __restrict__ beta,
    float* __restrict__ scale, float* __restrict__ shift) {
  const int c = threadIdx.x;
  float s = 0.f, s2 = 0.f;
  for (int g = 0; g < 256; ++g) { s += ps[g * 256 + c]; s2 += ps2[g * 256 + c]; }
  const float mean = s * (1.f / (float)M_);
  const float var = s2 * (1.f / (float)M_) - mean * mean;
  const float rstd = rsqrtf(var + 1e-5f);
  scale[c] = gamma[c] * rstd;
  shift[c] = beta[c] - mean * gamma[c] * rstd;
}

// ---------------------------------------------------------------- kernel E
// y = relu(attn*scale + shift + x), transposed back to [B][C][81] via LDS.
__global__ __launch_bounds__(256) void bn_apply_kernel(
    const float* __restrict__ qkv, const float* __restrict__ x,
    const float* __restrict__ scale, const float* __restrict__ shift,
    float* __restrict__ y) {
  __shared__ float t[N_ * 65];
  const int b = blockIdx.x, tid = threadIdx.x;
  for (int c0 = 0; c0 < 256; c0 += 64) {
    __syncthreads();
    for (int e = tid; e < N_ * 64; e += 256) {
      int n = e >> 6, c = e & 63;
      t[n * 65 + c] = qkv[((size_t)b * N_ + n) * 768 + c0 + c];
    }
    __syncthreads();
    for (int f = tid; f < 64 * N_; f += 256) {
      int c = f / N_, n = f - c * N_;
      float o = t[n * 65 + c];
      size_t gi = (size_t)b * (C_ * N_) + (size_t)(c0 + c) * N_ + n;
      float bn = o * scale[c0 + c] + shift[c0 + c];
      float v = bn + x[gi];
      y[gi] = v > 0.f ? v : 0.f;
    }
  }
}

// ----------------------------------------------------------------
extern "C" void kernel_launch(void* const* d_in, const int* in_sizes, int n_in,
                              void* d_out, int out_size, void* d_ws,
                              size_t ws_size, hipStream_t stream) {
  const float* x     = (const float*)d_in[0];
  const float* wq    = (const float*)d_in[1];
  const float* bq    = (const float*)d_in[2];
  const float* wk    = (const float*)d_in[3];
  const float* bk    = (const float*)d_in[4];
  const float* wv    = (const float*)d_in[5];
  const float* bv    = (const float*)d_in[6];
  const float* a     = (const float*)d_in[7];
  const float* gamma = (const float*)d_in[8];
  const float* beta  = (const float*)d_in[9];
  float* out = (float*)d_out;

  float*  qkv  = (float*)d_ws;                          // M*768 f32
  ushort* tokb = (ushort*)(qkv + (size_t)M_ * 768);     // M*256 bf16
  ushort* wcat = tokb + (size_t)M_ * 256;               // 768*256 bf16
  float*  bcat = (float*)(wcat + 768 * 256);            // 768 f32
  int*    kidx = (int*)(bcat + 768);                    // M*9 int
  float*  ps   = (float*)(kidx + (size_t)M_ * KNN);     // 256*256
  float*  ps2  = ps + 256 * 256;                        // 256*256
  float*  scale = ps2 + 256 * 256;                      // 256
  float*  shift = scale + 256;                          // 256

  knn_tok_kernel<<<B_, 256, 0, stream>>>(x, tokb, kidx);
  pack_w_kernel<<<768, 256, 0, stream>>>(wq, bq, wk, bk, wv, bv, wcat, bcat);
  qkv_mfma_kernel<<<dim3(M_ / 128, 6), 256, 0, stream>>>(tokb, wcat, bcat, qkv);
  attn_kernel<<<M_ / 4, 256, 0, stream>>>(qkv, kidx, a, qkv);
  bn_partial_kernel<<<256, 256, 0, stream>>>(qkv, ps, ps2);
  bn_finalize_kernel<<<1, 256, 0, stream>>>(ps, ps2, gamma, beta, scale, shift);
  bn_apply_kernel<<<B_, 256, 0, stream>>>(qkv, x, scale, shift, out);
}